// Round 3
// baseline (31.581 us; speedup 1.0000x reference)
//
#include <hip/hip_runtime.h>
#include <math.h>

// Problem constants (match reference)
#define BB 8192
#define NN 128
// SIGMA1 = 0.01, ALPHA = BETA = 0.5

typedef float vf2 __attribute__((ext_vector_type(2)));

constexpr int BLOCK = 256;
constexpr int EPT = 2;                              // elements per thread
constexpr int GRID = (BB * NN) / (BLOCK * EPT);     // 2048 blocks -> 8 blocks/CU, 32 waves/CU

// Stage 1: per-block partial sums of
//   s1 = sum log(niw_var)          (= psi_d - log(denom))
//   s2 = sum 1/niw_var             (= denom * exp(-psi_d)); SIGMA1 applied later
//   s3 = sum d^2 / niw_var
//   s4 = sum |d| * (lmbda + nu)
__global__ __launch_bounds__(BLOCK) void niw_reduce_kernel(
    const float* __restrict__ y, const float* __restrict__ mu,
    const float* __restrict__ lmbda, const float* __restrict__ psi,
    const float* __restrict__ nu, double* __restrict__ partials)
{
    const int t = blockIdx.x * BLOCK + threadIdx.x;
    const int e = t * EPT;               // first element index (even)
    const int b = e >> 7;                // row (N=128)
    const int j = e & 127;               // col within row (even)

    // --- scattered psi diagonal loads first: longest latency, no reuse -> nt
    const float* prow = psi + (size_t)b * (NN * NN) + (size_t)j * (NN + 1);
    const float pd0 = __builtin_nontemporal_load(prow);
    const float pd1 = __builtin_nontemporal_load(prow + (NN + 1));

    // --- contiguous streams, float2 per thread, non-temporal (read-once)
    const vf2 yv  = __builtin_nontemporal_load(reinterpret_cast<const vf2*>(y + e));
    const vf2 muv = __builtin_nontemporal_load(reinterpret_cast<const vf2*>(mu + e));
    const vf2 lmv = __builtin_nontemporal_load(reinterpret_cast<const vf2*>(lmbda + e));
    const vf2 nuv = __builtin_nontemporal_load(reinterpret_cast<const vf2*>(nu + e));

    const float pd[2] = {pd0, pd1};

    float s1 = 0.f, s2 = 0.f, s3 = 0.f, s4 = 0.f;
#pragma unroll
    for (int k = 0; k < 2; ++k) {
        float yk = yv[k];
        yk = (yk != yk) ? 0.0f : yk;     // nan_to_num
        const float d = muv[k] - yk;
        const float denom = lmv[k] * (nuv[k] - (float)(NN + 1));  // lmbda*(nu-n-1)
        s1 += pd[k] - __logf(denom);                              // log(niw_var)
        const float inv_v = denom * __expf(-pd[k]);               // 1/niw_var
        s2 += inv_v;
        s3 += d * d * inv_v;
        s4 += fabsf(d) * (lmv[k] + nuv[k]);
    }

    // wave (64-lane) reduction in float (threshold is ~1.8e5 abs; fp32 is ample)
#pragma unroll
    for (int off = 32; off > 0; off >>= 1) {
        s1 += __shfl_down(s1, off);
        s2 += __shfl_down(s2, off);
        s3 += __shfl_down(s3, off);
        s4 += __shfl_down(s4, off);
    }

    __shared__ float sh[4][4];           // [wave][accum]
    const int wave = threadIdx.x >> 6;
    const int lane = threadIdx.x & 63;
    if (lane == 0) {
        sh[wave][0] = s1; sh[wave][1] = s2; sh[wave][2] = s3; sh[wave][3] = s4;
    }
    __syncthreads();
    if (threadIdx.x == 0) {
        double t1 = 0, t2 = 0, t3 = 0, t4 = 0;
        for (int w = 0; w < 4; ++w) {
            t1 += sh[w][0]; t2 += sh[w][1]; t3 += sh[w][2]; t4 += sh[w][3];
        }
        double* p = partials + (size_t)blockIdx.x * 4;
        p[0] = t1; p[1] = t2; p[2] = t3; p[3] = t4;
    }
}

// Stage 2: single block sums the GRID partials, emits (loss, temporal, error)
__global__ __launch_bounds__(256) void niw_finalize_kernel(
    const double* __restrict__ partials, float* __restrict__ out)
{
    double t1 = 0, t2 = 0, t3 = 0, t4 = 0;
    for (int i = threadIdx.x; i < GRID; i += 256) {
        const double* p = partials + (size_t)i * 4;
        t1 += p[0]; t2 += p[1]; t3 += p[2]; t4 += p[3];
    }
#pragma unroll
    for (int off = 32; off > 0; off >>= 1) {
        t1 += __shfl_down(t1, off);
        t2 += __shfl_down(t2, off);
        t3 += __shfl_down(t3, off);
        t4 += __shfl_down(t4, off);
    }
    __shared__ double sh[4][4];
    const int wave = threadIdx.x >> 6;
    const int lane = threadIdx.x & 63;
    if (lane == 0) {
        sh[wave][0] = t1; sh[wave][1] = t2; sh[wave][2] = t3; sh[wave][3] = t4;
    }
    __syncthreads();
    if (threadIdx.x == 0) {
        double S1 = 0, S2 = 0, S3 = 0, S4 = 0;
        for (int w = 0; w < 4; ++w) {
            S1 += sh[w][0]; S2 += sh[w][1]; S3 += sh[w][2]; S4 += sh[w][3];
        }
        const double SIGMA1 = 0.01;
        const double n = (double)NN;
        const double Bd = (double)BB;
        // temporal = 0.5 * ( S1 - B*n*log(SIGMA1) - B*n + SIGMA1*S2 + S3 )
        const double temporal =
            0.5 * (S1 - Bd * n * log(SIGMA1) - Bd * n + SIGMA1 * S2 + S3);
        const double error = S4 / Bd;
        const double loss = 0.5 * temporal + 0.5 * error;
        out[0] = (float)loss;
        out[1] = (float)temporal;
        out[2] = (float)error;
    }
}

extern "C" void kernel_launch(void* const* d_in, const int* in_sizes, int n_in,
                              void* d_out, int out_size, void* d_ws, size_t ws_size,
                              hipStream_t stream) {
    const float* y     = (const float*)d_in[0];
    const float* mu    = (const float*)d_in[1];
    const float* lmbda = (const float*)d_in[2];
    const float* psi   = (const float*)d_in[3];
    const float* nu    = (const float*)d_in[4];
    float* out = (float*)d_out;
    double* partials = (double*)d_ws;    // needs GRID*4*8 = 64 KiB

    niw_reduce_kernel<<<GRID, BLOCK, 0, stream>>>(y, mu, lmbda, psi, nu, partials);
    niw_finalize_kernel<<<1, 256, 0, stream>>>(partials, out);
}